// Round 4
// baseline (1386.222 us; speedup 1.0000x reference)
//
#include <hip/hip_runtime.h>

#define NCLASSES 6
#define NGRAPHS 16
#define BN_EPS 1e-5f
#define SCAN_BLOCK 256
#define SCAN_ITEMS 16  // 4096 elements per block
#define WPAD 68        // padded row length (floats) for LDS weight rows

// ---------------- BN-fold: W'[l][mat][k][d] = W[l][k][d]*scale(l,mat,d);
// shift[l][mat][d] = be + (b - m)*scale ----------------
__global__ void k_fold(const float* __restrict__ W1, const float* __restrict__ b1,
                       const float* __restrict__ g1, const float* __restrict__ be1,
                       const float* __restrict__ m1, const float* __restrict__ v1,
                       const float* __restrict__ W2, const float* __restrict__ b2,
                       const float* __restrict__ g2, const float* __restrict__ be2,
                       const float* __restrict__ m2, const float* __restrict__ v2,
                       float* __restrict__ Wf, float* __restrict__ Sf) {
  int idx = blockIdx.x * blockDim.x + threadIdx.x;
  if (idx >= 3 * 2 * 64 * 64) return;
  int d = idx & 63;
  int k = (idx >> 6) & 63;
  int mat = (idx >> 12) & 1;
  int l = idx >> 13;
  const float* W = mat ? W2 : W1;
  const float* b = mat ? b2 : b1;
  const float* g = mat ? g2 : g1;
  const float* be = mat ? be2 : be1;
  const float* m = mat ? m2 : m1;
  const float* v = mat ? v2 : v1;
  float scale = g[l * 64 + d] * rsqrtf(v[l * 64 + d] + BN_EPS);
  Wf[idx] = W[(l * 64 + k) * 64 + d] * scale;
  if (k == 0)
    Sf[(l * 2 + mat) * 64 + d] = be[l * 64 + d] + (b[l * 64 + d] - m[l * 64 + d]) * scale;
}

// ---------------- CSR build ----------------
__global__ void k_deg(const int* __restrict__ dst, int nE, int* __restrict__ deg) {
  int e = blockIdx.x * blockDim.x + threadIdx.x;
  if (e < nE) atomicAdd(&deg[dst[e]], 1);
}

// pass 1: per-block (4096-chunk) sums
__global__ __launch_bounds__(SCAN_BLOCK) void k_scan_partial(
    const int* __restrict__ deg, int n, int* __restrict__ partials) {
  __shared__ int lds[SCAN_BLOCK];
  int t = threadIdx.x;
  int base = blockIdx.x * SCAN_BLOCK * SCAN_ITEMS + t * SCAN_ITEMS;
  int s = 0;
#pragma unroll
  for (int i = 0; i < SCAN_ITEMS; ++i) {
    int idx = base + i;
    if (idx < n) s += deg[idx];
  }
  lds[t] = s;
  __syncthreads();
  for (int off = SCAN_BLOCK / 2; off > 0; off >>= 1) {
    if (t < off) lds[t] += lds[t + off];
    __syncthreads();
  }
  if (t == 0) partials[blockIdx.x] = lds[0];
}

// pass 2: serial exclusive scan of block partials (nb ~ 25)
__global__ void k_scan_root(int* __restrict__ partials, int nb,
                            int* __restrict__ offs, int n) {
  if (threadIdx.x == 0) {
    int run = 0;
    for (int i = 0; i < nb; ++i) {
      int v = partials[i];
      partials[i] = run;
      run += v;
    }
    offs[n] = run;
  }
}

// pass 3: write exclusive offsets + cursor copy
__global__ __launch_bounds__(SCAN_BLOCK) void k_scan_write(
    const int* __restrict__ deg, int n, const int* __restrict__ partials,
    int* __restrict__ offs, int* __restrict__ cursor) {
  __shared__ int lds[SCAN_BLOCK];
  int t = threadIdx.x;
  int base = blockIdx.x * SCAN_BLOCK * SCAN_ITEMS + t * SCAN_ITEMS;
  int local[SCAN_ITEMS];
  int s = 0;
#pragma unroll
  for (int i = 0; i < SCAN_ITEMS; ++i) {
    int idx = base + i;
    int v = (idx < n) ? deg[idx] : 0;
    local[i] = v;
    s += v;
  }
  lds[t] = s;
  __syncthreads();
  int val = s;
  for (int off = 1; off < SCAN_BLOCK; off <<= 1) {
    int tmp = (t >= off) ? lds[t - off] : 0;
    __syncthreads();
    val += tmp;
    lds[t] = val;
    __syncthreads();
  }
  int run = partials[blockIdx.x] + val - s;  // exclusive prefix for this thread
#pragma unroll
  for (int i = 0; i < SCAN_ITEMS; ++i) {
    int idx = base + i;
    if (idx < n) {
      offs[idx] = run;
      cursor[idx] = run;
      run += local[i];
    }
  }
}

__global__ void k_fill(const int* __restrict__ src, const int* __restrict__ dstA, int nE,
                       int* __restrict__ cursor, int* __restrict__ csr_src) {
  int e = blockIdx.x * blockDim.x + threadIdx.x;
  if (e < nE) {
    int pos = atomicAdd(&cursor[dstA[e]], 1);
    csr_src[pos] = src[e];
  }
}

// ---------------- fused GIN layer ----------------
// z = h + sum_neigh(h); h' = relu(bn2(relu(bn1(z@W1))@W2))
// 4 waves/block; each wave processes 4 nodes per iteration; lane d owns feature d.
// Weights live TRANSPOSED+PADDED in LDS (shared across waves, no VGPR spill):
//   wXs[d * WPAD + k] = W[k][d]*bn_scale[d]
__global__ __launch_bounds__(256) void k_layer(
    const float* __restrict__ h_in, float* __restrict__ h_out,
    const int* __restrict__ offs, const int* __restrict__ csr_src,
    const float* __restrict__ Wf, const float* __restrict__ Sf, int n) {
  __shared__ __align__(16) float w1s[64 * WPAD];
  __shared__ __align__(16) float w2s[64 * WPAD];
  __shared__ __align__(16) float zb[4][4][64];
  const int lane = threadIdx.x & 63;
  const int wslot = threadIdx.x >> 6;

  // stage weights transposed (one-time)
  for (int i = threadIdx.x; i < 4096; i += 256) {
    int k = i >> 6, d = i & 63;
    w1s[d * WPAD + k] = Wf[i];
    w2s[d * WPAD + k] = Wf[4096 + i];
  }
  const float s1 = Sf[lane];
  const float s2 = Sf[64 + lane];
  __syncthreads();

  const float* w1row = &w1s[lane * WPAD];
  const float* w2row = &w2s[lane * WPAD];

  int gw = blockIdx.x * 4 + wslot;
  int nwave = gridDim.x * 4;
  for (int nb = gw * 4; nb < n; nb += nwave * 4) {
    float acc[4];
#pragma unroll
    for (int t = 0; t < 4; ++t)
      acc[t] = (nb + t < n) ? h_in[(size_t)(nb + t) * 64 + lane] : 0.f;

    // gather (atomic-free via CSR); 8-deep ILP per node
#pragma unroll
    for (int t = 0; t < 4; ++t) {
      int node = nb + t;
      if (node < n) {
        int e0 = offs[node], e1 = offs[node + 1];
        int e = e0;
        float a0 = 0.f, a1 = 0.f, a2 = 0.f, a3 = 0.f;
        float a4 = 0.f, a5 = 0.f, a6 = 0.f, a7 = 0.f;
        for (; e + 7 < e1; e += 8) {
          int q0 = csr_src[e], q1 = csr_src[e + 1];
          int q2 = csr_src[e + 2], q3 = csr_src[e + 3];
          int q4 = csr_src[e + 4], q5 = csr_src[e + 5];
          int q6 = csr_src[e + 6], q7 = csr_src[e + 7];
          a0 += h_in[(size_t)q0 * 64 + lane];
          a1 += h_in[(size_t)q1 * 64 + lane];
          a2 += h_in[(size_t)q2 * 64 + lane];
          a3 += h_in[(size_t)q3 * 64 + lane];
          a4 += h_in[(size_t)q4 * 64 + lane];
          a5 += h_in[(size_t)q5 * 64 + lane];
          a6 += h_in[(size_t)q6 * 64 + lane];
          a7 += h_in[(size_t)q7 * 64 + lane];
        }
        for (; e < e1; ++e) a0 += h_in[(size_t)csr_src[e] * 64 + lane];
        acc[t] += ((a0 + a1) + (a2 + a3)) + ((a4 + a5) + (a6 + a7));
      }
    }

    // publish z to per-wave LDS slots (wave-synchronous; ensure prior reads done)
    asm volatile("s_waitcnt lgkmcnt(0)" ::: "memory");
#pragma unroll
    for (int t = 0; t < 4; ++t) zb[wslot][t][lane] = acc[t];
    asm volatile("s_waitcnt lgkmcnt(0)" ::: "memory");

    // matmul1: p[t] = s1 + sum_k z[t][k] * W1t[lane][k]
    float p[4] = {s1, s1, s1, s1};
#pragma unroll
    for (int k0 = 0; k0 < 64; k0 += 4) {
      float4 w4 = *reinterpret_cast<const float4*>(w1row + k0);
#pragma unroll
      for (int t = 0; t < 4; ++t) {
        float4 z4 = *reinterpret_cast<const float4*>(&zb[wslot][t][k0]);
        p[t] = fmaf(z4.x, w4.x, p[t]);
        p[t] = fmaf(z4.y, w4.y, p[t]);
        p[t] = fmaf(z4.z, w4.z, p[t]);
        p[t] = fmaf(z4.w, w4.w, p[t]);
      }
    }

    // relu, publish back
    asm volatile("s_waitcnt lgkmcnt(0)" ::: "memory");
#pragma unroll
    for (int t = 0; t < 4; ++t) zb[wslot][t][lane] = fmaxf(p[t], 0.f);
    asm volatile("s_waitcnt lgkmcnt(0)" ::: "memory");

    // matmul2
    float q[4] = {s2, s2, s2, s2};
#pragma unroll
    for (int k0 = 0; k0 < 64; k0 += 4) {
      float4 w4 = *reinterpret_cast<const float4*>(w2row + k0);
#pragma unroll
      for (int t = 0; t < 4; ++t) {
        float4 z4 = *reinterpret_cast<const float4*>(&zb[wslot][t][k0]);
        q[t] = fmaf(z4.x, w4.x, q[t]);
        q[t] = fmaf(z4.y, w4.y, q[t]);
        q[t] = fmaf(z4.z, w4.z, q[t]);
        q[t] = fmaf(z4.w, w4.w, q[t]);
      }
    }

#pragma unroll
    for (int t = 0; t < 4; ++t)
      if (nb + t < n) h_out[(size_t)(nb + t) * 64 + lane] = fmaxf(q[t], 0.f);
  }
}

// ---------------- pooling: block-local LDS accumulation then global atomics ----------------
__global__ __launch_bounds__(256) void k_pool(const float* __restrict__ h,
                                              const int* __restrict__ batch, int n,
                                              float* __restrict__ gsum,
                                              float* __restrict__ gcnt) {
  __shared__ float lsum[NGRAPHS * 64];
  __shared__ float lcnt[NGRAPHS];
  for (int i = threadIdx.x; i < NGRAPHS * 64; i += 256) lsum[i] = 0.f;
  if (threadIdx.x < NGRAPHS) lcnt[threadIdx.x] = 0.f;
  __syncthreads();
  int lane = threadIdx.x & 63, wslot = threadIdx.x >> 6;
  int wave = blockIdx.x * 4 + wslot, nw = gridDim.x * 4;
  for (int node = wave; node < n; node += nw) {
    int g = batch[node];
    atomicAdd(&lsum[g * 64 + lane], h[(size_t)node * 64 + lane]);
    if (lane == 0) atomicAdd(&lcnt[g], 1.f);
  }
  __syncthreads();
  for (int i = threadIdx.x; i < NGRAPHS * 64; i += 256) atomicAdd(&gsum[i], lsum[i]);
  if (threadIdx.x < NGRAPHS) atomicAdd(&gcnt[threadIdx.x], lcnt[threadIdx.x]);
}

// ---------------- heads: pooled@wp+bp, pooled@ws+bs ----------------
__global__ void k_head(const float* __restrict__ gsum, const float* __restrict__ gcnt,
                       const float* __restrict__ wp, const float* __restrict__ bp,
                       const float* __restrict__ wsec, const float* __restrict__ bsec,
                       float* __restrict__ out) {
  int t = threadIdx.x;
  if (t >= NGRAPHS * NCLASSES) return;
  int g = t / NCLASSES, c = t % NCLASSES;
  float inv = 1.f / fmaxf(gcnt[g], 1.f);
  float p = 0.f, s = 0.f;
  for (int d = 0; d < 64; ++d) {
    float pd = gsum[g * 64 + d] * inv;
    p = fmaf(pd, wp[d * NCLASSES + c], p);
    s = fmaf(pd, wsec[d * NCLASSES + c], s);
  }
  out[t] = p + bp[c];
  out[NGRAPHS * NCLASSES + t] = s + bsec[c];
}

extern "C" void kernel_launch(void* const* d_in, const int* in_sizes, int n_in,
                              void* d_out, int out_size, void* d_ws, size_t ws_size,
                              hipStream_t stream) {
  const float* x = (const float*)d_in[0];
  const int* ei = (const int*)d_in[1];
  const int* batch = (const int*)d_in[2];
  const float* W1 = (const float*)d_in[3];
  const float* b1 = (const float*)d_in[4];
  const float* g1 = (const float*)d_in[5];
  const float* be1 = (const float*)d_in[6];
  const float* m1 = (const float*)d_in[7];
  const float* v1 = (const float*)d_in[8];
  const float* W2 = (const float*)d_in[9];
  const float* b2 = (const float*)d_in[10];
  const float* g2 = (const float*)d_in[11];
  const float* be2 = (const float*)d_in[12];
  const float* m2 = (const float*)d_in[13];
  const float* v2 = (const float*)d_in[14];
  const float* wp = (const float*)d_in[15];
  const float* bp = (const float*)d_in[16];
  const float* wsec = (const float*)d_in[17];
  const float* bsec = (const float*)d_in[18];

  const int nE = in_sizes[1] / 2;
  const int n = in_sizes[0] / 64;

  char* p = (char*)d_ws;
  auto alloc = [&](size_t bytes) {
    char* r = p;
    p += (bytes + 255) & ~(size_t)255;
    return r;
  };
  float* hA = (float*)alloc((size_t)n * 64 * 4);
  float* hB = (float*)alloc((size_t)n * 64 * 4);
  int* csr = (int*)alloc((size_t)nE * 4);
  int* offs = (int*)alloc((size_t)(n + 1) * 4);
  int* cursor = (int*)alloc((size_t)n * 4);
  int* deg = (int*)alloc((size_t)n * 4);
  int* partials = (int*)alloc(1024 * 4);
  float* Wf = (float*)alloc(3 * 2 * 64 * 64 * 4);
  float* Sf = (float*)alloc(3 * 2 * 64 * 4);
  float* gsum = (float*)alloc(NGRAPHS * 64 * 4);
  float* gcnt = (float*)alloc(NGRAPHS * 4);

  hipMemsetAsync(deg, 0, (size_t)n * 4, stream);
  hipMemsetAsync(gsum, 0, NGRAPHS * 64 * 4, stream);
  hipMemsetAsync(gcnt, 0, NGRAPHS * 4, stream);

  k_fold<<<(3 * 2 * 64 * 64 + 255) / 256, 256, 0, stream>>>(
      W1, b1, g1, be1, m1, v1, W2, b2, g2, be2, m2, v2, Wf, Sf);
  k_deg<<<(nE + 255) / 256, 256, 0, stream>>>(ei + nE, nE, deg);

  const int nb = (n + SCAN_BLOCK * SCAN_ITEMS - 1) / (SCAN_BLOCK * SCAN_ITEMS);
  k_scan_partial<<<nb, SCAN_BLOCK, 0, stream>>>(deg, n, partials);
  k_scan_root<<<1, 64, 0, stream>>>(partials, nb, offs, n);
  k_scan_write<<<nb, SCAN_BLOCK, 0, stream>>>(deg, n, partials, offs, cursor);

  k_fill<<<(nE + 255) / 256, 256, 0, stream>>>(ei, ei + nE, nE, cursor, csr);

  const int LAYER_BLOCKS = 1024;  // 4 blocks/CU (LDS-capped), 16 waves/CU
  k_layer<<<LAYER_BLOCKS, 256, 0, stream>>>(x, hA, offs, csr, Wf + 0 * 8192, Sf + 0 * 128, n);
  k_layer<<<LAYER_BLOCKS, 256, 0, stream>>>(hA, hB, offs, csr, Wf + 1 * 8192, Sf + 1 * 128, n);
  k_layer<<<LAYER_BLOCKS, 256, 0, stream>>>(hB, hA, offs, csr, Wf + 2 * 8192, Sf + 2 * 128, n);

  k_pool<<<512, 256, 0, stream>>>(hA, batch, n, gsum, gcnt);
  k_head<<<1, 128, 0, stream>>>(gsum, gcnt, wp, bp, wsec, bsec, (float*)d_out);
}

// Round 5
// 693.195 us; speedup vs baseline: 1.9998x; 1.9998x over previous
//
#include <hip/hip_runtime.h>

#define NCLASSES 6
#define NGRAPHS 16
#define BN_EPS 1e-5f
#define SCAN_BLOCK 256
#define SCAN_ITEMS 16  // 4096 elements per block

// ---------------- BN-fold: W'[l][mat][k][d] = W[l][k][d]*scale(l,mat,d);
// shift[l][mat][d] = be + (b - m)*scale ----------------
__global__ void k_fold(const float* __restrict__ W1, const float* __restrict__ b1,
                       const float* __restrict__ g1, const float* __restrict__ be1,
                       const float* __restrict__ m1, const float* __restrict__ v1,
                       const float* __restrict__ W2, const float* __restrict__ b2,
                       const float* __restrict__ g2, const float* __restrict__ be2,
                       const float* __restrict__ m2, const float* __restrict__ v2,
                       float* __restrict__ Wf, float* __restrict__ Sf) {
  int idx = blockIdx.x * blockDim.x + threadIdx.x;
  if (idx >= 3 * 2 * 64 * 64) return;
  int d = idx & 63;
  int k = (idx >> 6) & 63;
  int mat = (idx >> 12) & 1;
  int l = idx >> 13;
  const float* W = mat ? W2 : W1;
  const float* b = mat ? b2 : b1;
  const float* g = mat ? g2 : g1;
  const float* be = mat ? be2 : be1;
  const float* m = mat ? m2 : m1;
  const float* v = mat ? v2 : v1;
  float scale = g[l * 64 + d] * rsqrtf(v[l * 64 + d] + BN_EPS);
  Wf[idx] = W[(l * 64 + k) * 64 + d] * scale;
  if (k == 0)
    Sf[(l * 2 + mat) * 64 + d] = be[l * 64 + d] + (b[l * 64 + d] - m[l * 64 + d]) * scale;
}

// ---------------- CSR build ----------------
__global__ void k_deg(const int* __restrict__ dst, int nE, int* __restrict__ deg) {
  int e = blockIdx.x * blockDim.x + threadIdx.x;
  if (e < nE) atomicAdd(&deg[dst[e]], 1);
}

__global__ __launch_bounds__(SCAN_BLOCK) void k_scan_partial(
    const int* __restrict__ deg, int n, int* __restrict__ partials) {
  __shared__ int lds[SCAN_BLOCK];
  int t = threadIdx.x;
  int base = blockIdx.x * SCAN_BLOCK * SCAN_ITEMS + t * SCAN_ITEMS;
  int s = 0;
#pragma unroll
  for (int i = 0; i < SCAN_ITEMS; ++i) {
    int idx = base + i;
    if (idx < n) s += deg[idx];
  }
  lds[t] = s;
  __syncthreads();
  for (int off = SCAN_BLOCK / 2; off > 0; off >>= 1) {
    if (t < off) lds[t] += lds[t + off];
    __syncthreads();
  }
  if (t == 0) partials[blockIdx.x] = lds[0];
}

__global__ void k_scan_root(int* __restrict__ partials, int nb,
                            int* __restrict__ offs, int n) {
  if (threadIdx.x == 0) {
    int run = 0;
    for (int i = 0; i < nb; ++i) {
      int v = partials[i];
      partials[i] = run;
      run += v;
    }
    offs[n] = run;
  }
}

__global__ __launch_bounds__(SCAN_BLOCK) void k_scan_write(
    const int* __restrict__ deg, int n, const int* __restrict__ partials,
    int* __restrict__ offs, int* __restrict__ cursor) {
  __shared__ int lds[SCAN_BLOCK];
  int t = threadIdx.x;
  int base = blockIdx.x * SCAN_BLOCK * SCAN_ITEMS + t * SCAN_ITEMS;
  int local[SCAN_ITEMS];
  int s = 0;
#pragma unroll
  for (int i = 0; i < SCAN_ITEMS; ++i) {
    int idx = base + i;
    int v = (idx < n) ? deg[idx] : 0;
    local[i] = v;
    s += v;
  }
  lds[t] = s;
  __syncthreads();
  int val = s;
  for (int off = 1; off < SCAN_BLOCK; off <<= 1) {
    int tmp = (t >= off) ? lds[t - off] : 0;
    __syncthreads();
    val += tmp;
    lds[t] = val;
    __syncthreads();
  }
  int run = partials[blockIdx.x] + val - s;
#pragma unroll
  for (int i = 0; i < SCAN_ITEMS; ++i) {
    int idx = base + i;
    if (idx < n) {
      offs[idx] = run;
      cursor[idx] = run;
      run += local[i];
    }
  }
}

__global__ void k_fill(const int* __restrict__ src, const int* __restrict__ dstA, int nE,
                       int* __restrict__ cursor, int* __restrict__ csr_src) {
  int e = blockIdx.x * blockDim.x + threadIdx.x;
  if (e < nE) {
    int pos = atomicAdd(&cursor[dstA[e]], 1);
    csr_src[pos] = src[e];
  }
}

// ---------------- gather only: z = h[node] + sum_neigh h  ----------------
// Max occupancy (VGPR<=64, 8 waves/EU = 32 waves/CU); 8-deep load ILP.
__global__ __launch_bounds__(256, 8) void k_gather(
    const float* __restrict__ h_in, float* __restrict__ z,
    const int* __restrict__ offs, const int* __restrict__ csr_src, int n) {
  const int lane = threadIdx.x & 63;
  int wave = blockIdx.x * 4 + (threadIdx.x >> 6);
  int nwaves = gridDim.x * 4;
  for (int node = wave; node < n; node += nwaves) {
    float acc = h_in[(size_t)node * 64 + lane];
    int e0 = offs[node], e1 = offs[node + 1];
    int e = e0;
    float a0 = 0.f, a1 = 0.f, a2 = 0.f, a3 = 0.f;
    float a4 = 0.f, a5 = 0.f, a6 = 0.f, a7 = 0.f;
    for (; e + 7 < e1; e += 8) {
      int q0 = csr_src[e], q1 = csr_src[e + 1];
      int q2 = csr_src[e + 2], q3 = csr_src[e + 3];
      int q4 = csr_src[e + 4], q5 = csr_src[e + 5];
      int q6 = csr_src[e + 6], q7 = csr_src[e + 7];
      a0 += h_in[(size_t)q0 * 64 + lane];
      a1 += h_in[(size_t)q1 * 64 + lane];
      a2 += h_in[(size_t)q2 * 64 + lane];
      a3 += h_in[(size_t)q3 * 64 + lane];
      a4 += h_in[(size_t)q4 * 64 + lane];
      a5 += h_in[(size_t)q5 * 64 + lane];
      a6 += h_in[(size_t)q6 * 64 + lane];
      a7 += h_in[(size_t)q7 * 64 + lane];
    }
    for (; e < e1; ++e) a0 += h_in[(size_t)csr_src[e] * 64 + lane];
    acc += ((a0 + a1) + (a2 + a3)) + ((a4 + a5) + (a6 + a7));
    z[(size_t)node * 64 + lane] = acc;
  }
}

// ---------------- streaming MLP: h' = relu(bn2(relu(bn1(z@W1))@W2)) ----------------
// Weights in VGPRs (launch_bounds cap 256 regs -> no spill); z via LDS broadcast.
__global__ __launch_bounds__(256, 2) void k_mlp(
    const float* __restrict__ z_in, float* __restrict__ h_out,
    const float* __restrict__ Wf, const float* __restrict__ Sf, int n) {
  __shared__ __align__(16) float zbuf[4][64];
  const int lane = threadIdx.x & 63;
  const int wslot = threadIdx.x >> 6;

  float w1[64], w2[64];
#pragma unroll
  for (int k = 0; k < 64; ++k) {
    w1[k] = Wf[k * 64 + lane];
    w2[k] = Wf[4096 + k * 64 + lane];
  }
  const float s1 = Sf[lane];
  const float s2 = Sf[64 + lane];

  int wave = blockIdx.x * 4 + wslot;
  int nwaves = gridDim.x * 4;
  for (int node = wave; node < n; node += nwaves) {
    float zv = z_in[(size_t)node * 64 + lane];

    zbuf[wslot][lane] = zv;
    asm volatile("s_waitcnt lgkmcnt(0)" ::: "memory");

    float p0 = s1, p1 = 0.f, p2 = 0.f, p3 = 0.f;
#pragma unroll
    for (int k0 = 0; k0 < 64; k0 += 4) {
      float4 z4 = *reinterpret_cast<const float4*>(&zbuf[wslot][k0]);
      p0 = fmaf(z4.x, w1[k0 + 0], p0);
      p1 = fmaf(z4.y, w1[k0 + 1], p1);
      p2 = fmaf(z4.z, w1[k0 + 2], p2);
      p3 = fmaf(z4.w, w1[k0 + 3], p3);
    }
    float o1 = fmaxf((p0 + p1) + (p2 + p3), 0.f);

    asm volatile("" ::: "memory");
    zbuf[wslot][lane] = o1;
    asm volatile("s_waitcnt lgkmcnt(0)" ::: "memory");

    float q0 = s2, q1 = 0.f, q2 = 0.f, q3 = 0.f;
#pragma unroll
    for (int k0 = 0; k0 < 64; k0 += 4) {
      float4 z4 = *reinterpret_cast<const float4*>(&zbuf[wslot][k0]);
      q0 = fmaf(z4.x, w2[k0 + 0], q0);
      q1 = fmaf(z4.y, w2[k0 + 1], q1);
      q2 = fmaf(z4.z, w2[k0 + 2], q2);
      q3 = fmaf(z4.w, w2[k0 + 3], q3);
    }
    h_out[(size_t)node * 64 + lane] = fmaxf((q0 + q1) + (q2 + q3), 0.f);
    asm volatile("" ::: "memory");
  }
}

// ---------------- pooling ----------------
__global__ __launch_bounds__(256) void k_pool(const float* __restrict__ h,
                                              const int* __restrict__ batch, int n,
                                              float* __restrict__ gsum,
                                              float* __restrict__ gcnt) {
  __shared__ float lsum[NGRAPHS * 64];
  __shared__ float lcnt[NGRAPHS];
  for (int i = threadIdx.x; i < NGRAPHS * 64; i += 256) lsum[i] = 0.f;
  if (threadIdx.x < NGRAPHS) lcnt[threadIdx.x] = 0.f;
  __syncthreads();
  int lane = threadIdx.x & 63, wslot = threadIdx.x >> 6;
  int wave = blockIdx.x * 4 + wslot, nw = gridDim.x * 4;
  for (int node = wave; node < n; node += nw) {
    int g = batch[node];
    atomicAdd(&lsum[g * 64 + lane], h[(size_t)node * 64 + lane]);
    if (lane == 0) atomicAdd(&lcnt[g], 1.f);
  }
  __syncthreads();
  for (int i = threadIdx.x; i < NGRAPHS * 64; i += 256) atomicAdd(&gsum[i], lsum[i]);
  if (threadIdx.x < NGRAPHS) atomicAdd(&gcnt[threadIdx.x], lcnt[threadIdx.x]);
}

// ---------------- heads ----------------
__global__ void k_head(const float* __restrict__ gsum, const float* __restrict__ gcnt,
                       const float* __restrict__ wp, const float* __restrict__ bp,
                       const float* __restrict__ wsec, const float* __restrict__ bsec,
                       float* __restrict__ out) {
  int t = threadIdx.x;
  if (t >= NGRAPHS * NCLASSES) return;
  int g = t / NCLASSES, c = t % NCLASSES;
  float inv = 1.f / fmaxf(gcnt[g], 1.f);
  float p = 0.f, s = 0.f;
  for (int d = 0; d < 64; ++d) {
    float pd = gsum[g * 64 + d] * inv;
    p = fmaf(pd, wp[d * NCLASSES + c], p);
    s = fmaf(pd, wsec[d * NCLASSES + c], s);
  }
  out[t] = p + bp[c];
  out[NGRAPHS * NCLASSES + t] = s + bsec[c];
}

extern "C" void kernel_launch(void* const* d_in, const int* in_sizes, int n_in,
                              void* d_out, int out_size, void* d_ws, size_t ws_size,
                              hipStream_t stream) {
  const float* x = (const float*)d_in[0];
  const int* ei = (const int*)d_in[1];
  const int* batch = (const int*)d_in[2];
  const float* W1 = (const float*)d_in[3];
  const float* b1 = (const float*)d_in[4];
  const float* g1 = (const float*)d_in[5];
  const float* be1 = (const float*)d_in[6];
  const float* m1 = (const float*)d_in[7];
  const float* v1 = (const float*)d_in[8];
  const float* W2 = (const float*)d_in[9];
  const float* b2 = (const float*)d_in[10];
  const float* g2 = (const float*)d_in[11];
  const float* be2 = (const float*)d_in[12];
  const float* m2 = (const float*)d_in[13];
  const float* v2 = (const float*)d_in[14];
  const float* wp = (const float*)d_in[15];
  const float* bp = (const float*)d_in[16];
  const float* wsec = (const float*)d_in[17];
  const float* bsec = (const float*)d_in[18];

  const int nE = in_sizes[1] / 2;
  const int n = in_sizes[0] / 64;

  char* p = (char*)d_ws;
  auto alloc = [&](size_t bytes) {
    char* r = p;
    p += (bytes + 255) & ~(size_t)255;
    return r;
  };
  float* hA = (float*)alloc((size_t)n * 64 * 4);
  float* hB = (float*)alloc((size_t)n * 64 * 4);
  float* zbuf = (float*)alloc((size_t)n * 64 * 4);
  int* csr = (int*)alloc((size_t)nE * 4);
  int* offs = (int*)alloc((size_t)(n + 1) * 4);
  int* cursor = (int*)alloc((size_t)n * 4);
  int* deg = (int*)alloc((size_t)n * 4);
  int* partials = (int*)alloc(1024 * 4);
  float* Wf = (float*)alloc(3 * 2 * 64 * 64 * 4);
  float* Sf = (float*)alloc(3 * 2 * 64 * 4);
  float* gsum = (float*)alloc(NGRAPHS * 64 * 4);
  float* gcnt = (float*)alloc(NGRAPHS * 4);

  hipMemsetAsync(deg, 0, (size_t)n * 4, stream);
  hipMemsetAsync(gsum, 0, NGRAPHS * 64 * 4, stream);
  hipMemsetAsync(gcnt, 0, NGRAPHS * 4, stream);

  k_fold<<<(3 * 2 * 64 * 64 + 255) / 256, 256, 0, stream>>>(
      W1, b1, g1, be1, m1, v1, W2, b2, g2, be2, m2, v2, Wf, Sf);
  k_deg<<<(nE + 255) / 256, 256, 0, stream>>>(ei + nE, nE, deg);

  const int nb = (n + SCAN_BLOCK * SCAN_ITEMS - 1) / (SCAN_BLOCK * SCAN_ITEMS);
  k_scan_partial<<<nb, SCAN_BLOCK, 0, stream>>>(deg, n, partials);
  k_scan_root<<<1, 64, 0, stream>>>(partials, nb, offs, n);
  k_scan_write<<<nb, SCAN_BLOCK, 0, stream>>>(deg, n, partials, offs, cursor);

  k_fill<<<(nE + 255) / 256, 256, 0, stream>>>(ei, ei + nE, nE, cursor, csr);

  const int GB = 2048;  // gather: 8 blocks/CU, 32 waves/CU
  const int MB = 2048;  // mlp: grid-stride streaming
  const float* hin = x;
  float* houts[3] = {hA, hB, hA};
  for (int l = 0; l < 3; ++l) {
    k_gather<<<GB, 256, 0, stream>>>(hin, zbuf, offs, csr, n);
    k_mlp<<<MB, 256, 0, stream>>>(zbuf, houts[l], Wf + l * 8192, Sf + l * 128, n);
    hin = houts[l];
  }

  k_pool<<<512, 256, 0, stream>>>(hA, batch, n, gsum, gcnt);
  k_head<<<1, 128, 0, stream>>>(gsum, gcnt, wp, bp, wsec, bsec, (float*)d_out);
}

// Round 6
// 559.981 us; speedup vs baseline: 2.4755x; 1.2379x over previous
//
#include <hip/hip_runtime.h>

#define NCLASSES 6
#define NGRAPHS 16
#define BN_EPS 1e-5f
#define SCAN_BLOCK 256
#define SCAN_ITEMS 16  // 4096 elements per scan block
#define NB2 128        // blocks for bucket count/scatter passes

// ---------------- BN-fold ----------------
__global__ void k_fold(const float* __restrict__ W1, const float* __restrict__ b1,
                       const float* __restrict__ g1, const float* __restrict__ be1,
                       const float* __restrict__ m1, const float* __restrict__ v1,
                       const float* __restrict__ W2, const float* __restrict__ b2,
                       const float* __restrict__ g2, const float* __restrict__ be2,
                       const float* __restrict__ m2, const float* __restrict__ v2,
                       float* __restrict__ Wf, float* __restrict__ Sf) {
  int idx = blockIdx.x * blockDim.x + threadIdx.x;
  if (idx >= 3 * 2 * 64 * 64) return;
  int d = idx & 63;
  int k = (idx >> 6) & 63;
  int mat = (idx >> 12) & 1;
  int l = idx >> 13;
  const float* W = mat ? W2 : W1;
  const float* b = mat ? b2 : b1;
  const float* g = mat ? g2 : g1;
  const float* be = mat ? be2 : be1;
  const float* m = mat ? m2 : m1;
  const float* v = mat ? v2 : v1;
  float scale = g[l * 64 + d] * rsqrtf(v[l * 64 + d] + BN_EPS);
  Wf[idx] = W[(l * 64 + k) * 64 + d] * scale;
  if (k == 0)
    Sf[(l * 2 + mat) * 64 + d] = be[l * 64 + d] + (b[l * 64 + d] - m[l * 64 + d]) * scale;
}

// ---------------- bucketed CSR build ----------------
// pass 1: per-block private histogram over buckets (bucket = dst>>8)
__global__ __launch_bounds__(256) void k_bcount(const int* __restrict__ dst, int nE,
                                                int chunk, int nbk,
                                                int* __restrict__ hist) {
  __shared__ int lcnt[512];
  for (int i = threadIdx.x; i < nbk; i += 256) lcnt[i] = 0;
  __syncthreads();
  int blk = blockIdx.x;
  int c0 = blk * chunk, c1 = min(nE, c0 + chunk);
  for (int e = c0 + threadIdx.x; e < c1; e += 256) atomicAdd(&lcnt[dst[e] >> 8], 1);
  __syncthreads();
  for (int k = threadIdx.x; k < nbk; k += 256) hist[k * NB2 + blk] = lcnt[k];
}

// hierarchical scan over hist (bucket-major flat array)
__global__ __launch_bounds__(SCAN_BLOCK) void k_scan_partial(
    const int* __restrict__ in, int n, int* __restrict__ partials) {
  __shared__ int lds[SCAN_BLOCK];
  int t = threadIdx.x;
  int base = blockIdx.x * SCAN_BLOCK * SCAN_ITEMS + t * SCAN_ITEMS;
  int s = 0;
#pragma unroll
  for (int i = 0; i < SCAN_ITEMS; ++i) {
    int idx = base + i;
    if (idx < n) s += in[idx];
  }
  lds[t] = s;
  __syncthreads();
  for (int off = SCAN_BLOCK / 2; off > 0; off >>= 1) {
    if (t < off) lds[t] += lds[t + off];
    __syncthreads();
  }
  if (t == 0) partials[blockIdx.x] = lds[0];
}

__global__ void k_scan_root(int* __restrict__ partials, int nb) {
  if (threadIdx.x == 0) {
    int run = 0;
    for (int i = 0; i < nb; ++i) {
      int v = partials[i];
      partials[i] = run;
      run += v;
    }
  }
}

__global__ __launch_bounds__(SCAN_BLOCK) void k_scan_write(
    const int* __restrict__ in, int n, const int* __restrict__ partials,
    int* __restrict__ out_excl) {
  __shared__ int lds[SCAN_BLOCK];
  int t = threadIdx.x;
  int base = blockIdx.x * SCAN_BLOCK * SCAN_ITEMS + t * SCAN_ITEMS;
  int local[SCAN_ITEMS];
  int s = 0;
#pragma unroll
  for (int i = 0; i < SCAN_ITEMS; ++i) {
    int idx = base + i;
    int v = (idx < n) ? in[idx] : 0;
    local[i] = v;
    s += v;
  }
  lds[t] = s;
  __syncthreads();
  int val = s;
  for (int off = 1; off < SCAN_BLOCK; off <<= 1) {
    int tmp = (t >= off) ? lds[t - off] : 0;
    __syncthreads();
    val += tmp;
    lds[t] = val;
    __syncthreads();
  }
  int run = partials[blockIdx.x] + val - s;
#pragma unroll
  for (int i = 0; i < SCAN_ITEMS; ++i) {
    int idx = base + i;
    if (idx < n) {
      out_excl[idx] = run;
      run += local[i];
    }
  }
}

// bucket base offsets: boff[k] = hist_base[k*NB2]; boff[nbk] = nE
__global__ void k_boff(const int* __restrict__ hist_base, int nbk, int nE,
                       int* __restrict__ boff) {
  int t = blockIdx.x * blockDim.x + threadIdx.x;
  if (t < nbk) boff[t] = hist_base[t * NB2];
  if (t == nbk) boff[nbk] = nE;
}

// pass 2: scatter (src,dst) pairs into per-(bucket,block) private ranges — no global atomics
__global__ __launch_bounds__(256) void k_bscatter(const int* __restrict__ src,
                                                  const int* __restrict__ dst, int nE,
                                                  int chunk, int nbk,
                                                  const int* __restrict__ hist_base,
                                                  int2* __restrict__ ebuf) {
  __shared__ int cur[512];
  int blk = blockIdx.x;
  for (int k = threadIdx.x; k < nbk; k += 256) cur[k] = hist_base[k * NB2 + blk];
  __syncthreads();
  int c0 = blk * chunk, c1 = min(nE, c0 + chunk);
  for (int e = c0 + threadIdx.x; e < c1; e += 256) {
    int d = dst[e];
    int pos = atomicAdd(&cur[d >> 8], 1);  // LDS atomic
    ebuf[pos] = make_int2(src[e], d);
  }
}

// pass 3: per-bucket counting sort -> offs + csr_src (single block owns bucket window)
__global__ __launch_bounds__(256) void k_bsort(const int2* __restrict__ ebuf,
                                               const int* __restrict__ boff, int nbk,
                                               int n, int nE, int* __restrict__ offs,
                                               int* __restrict__ csr_src) {
  __shared__ int cnt[256], sc[256], cur[256];
  int b = blockIdx.x, t = threadIdx.x;
  int e0 = boff[b], e1 = boff[b + 1];
  int node0 = b << 8;
  cnt[t] = 0;
  __syncthreads();
  for (int e = e0 + t; e < e1; e += 256) atomicAdd(&cnt[ebuf[e].y - node0], 1);
  __syncthreads();
  int v = cnt[t];
  sc[t] = v;
  __syncthreads();
  int val = v;
  for (int off = 1; off < 256; off <<= 1) {
    int tmp = (t >= off) ? sc[t - off] : 0;
    __syncthreads();
    val += tmp;
    sc[t] = val;
    __syncthreads();
  }
  int excl = val - v;
  int node = node0 + t;
  if (node < n) offs[node] = e0 + excl;
  cur[t] = e0 + excl;
  if (b == nbk - 1 && t == 0) offs[n] = nE;
  __syncthreads();
  for (int e = e0 + t; e < e1; e += 256) {
    int2 pr = ebuf[e];
    int pos = atomicAdd(&cur[pr.y - node0], 1);  // LDS atomic
    csr_src[pos] = pr.x;
  }
}

// ---------------- gather only: z = h[node] + sum_neigh h ----------------
__global__ __launch_bounds__(256, 8) void k_gather(
    const float* __restrict__ h_in, float* __restrict__ z,
    const int* __restrict__ offs, const int* __restrict__ csr_src, int n) {
  const int lane = threadIdx.x & 63;
  int wave = blockIdx.x * 4 + (threadIdx.x >> 6);
  int nwaves = gridDim.x * 4;
  for (int node = wave; node < n; node += nwaves) {
    float acc = h_in[(size_t)node * 64 + lane];
    int e0 = offs[node], e1 = offs[node + 1];
    int e = e0;
    float a0 = 0.f, a1 = 0.f, a2 = 0.f, a3 = 0.f;
    float a4 = 0.f, a5 = 0.f, a6 = 0.f, a7 = 0.f;
    for (; e + 7 < e1; e += 8) {
      int q0 = csr_src[e], q1 = csr_src[e + 1];
      int q2 = csr_src[e + 2], q3 = csr_src[e + 3];
      int q4 = csr_src[e + 4], q5 = csr_src[e + 5];
      int q6 = csr_src[e + 6], q7 = csr_src[e + 7];
      a0 += h_in[(size_t)q0 * 64 + lane];
      a1 += h_in[(size_t)q1 * 64 + lane];
      a2 += h_in[(size_t)q2 * 64 + lane];
      a3 += h_in[(size_t)q3 * 64 + lane];
      a4 += h_in[(size_t)q4 * 64 + lane];
      a5 += h_in[(size_t)q5 * 64 + lane];
      a6 += h_in[(size_t)q6 * 64 + lane];
      a7 += h_in[(size_t)q7 * 64 + lane];
    }
    for (; e < e1; ++e) a0 += h_in[(size_t)csr_src[e] * 64 + lane];
    acc += ((a0 + a1) + (a2 + a3)) + ((a4 + a5) + (a6 + a7));
    z[(size_t)node * 64 + lane] = acc;
  }
}

// ---------------- streaming MLP ----------------
__global__ __launch_bounds__(256, 2) void k_mlp(
    const float* __restrict__ z_in, float* __restrict__ h_out,
    const float* __restrict__ Wf, const float* __restrict__ Sf, int n) {
  __shared__ __align__(16) float zbuf[4][64];
  const int lane = threadIdx.x & 63;
  const int wslot = threadIdx.x >> 6;

  float w1[64], w2[64];
#pragma unroll
  for (int k = 0; k < 64; ++k) {
    w1[k] = Wf[k * 64 + lane];
    w2[k] = Wf[4096 + k * 64 + lane];
  }
  const float s1 = Sf[lane];
  const float s2 = Sf[64 + lane];

  int wave = blockIdx.x * 4 + wslot;
  int nwaves = gridDim.x * 4;
  for (int node = wave; node < n; node += nwaves) {
    float zv = z_in[(size_t)node * 64 + lane];

    zbuf[wslot][lane] = zv;
    asm volatile("s_waitcnt lgkmcnt(0)" ::: "memory");

    float p0 = s1, p1 = 0.f, p2 = 0.f, p3 = 0.f;
#pragma unroll
    for (int k0 = 0; k0 < 64; k0 += 4) {
      float4 z4 = *reinterpret_cast<const float4*>(&zbuf[wslot][k0]);
      p0 = fmaf(z4.x, w1[k0 + 0], p0);
      p1 = fmaf(z4.y, w1[k0 + 1], p1);
      p2 = fmaf(z4.z, w1[k0 + 2], p2);
      p3 = fmaf(z4.w, w1[k0 + 3], p3);
    }
    float o1 = fmaxf((p0 + p1) + (p2 + p3), 0.f);

    asm volatile("" ::: "memory");
    zbuf[wslot][lane] = o1;
    asm volatile("s_waitcnt lgkmcnt(0)" ::: "memory");

    float q0 = s2, q1 = 0.f, q2 = 0.f, q3 = 0.f;
#pragma unroll
    for (int k0 = 0; k0 < 64; k0 += 4) {
      float4 z4 = *reinterpret_cast<const float4*>(&zbuf[wslot][k0]);
      q0 = fmaf(z4.x, w2[k0 + 0], q0);
      q1 = fmaf(z4.y, w2[k0 + 1], q1);
      q2 = fmaf(z4.z, w2[k0 + 2], q2);
      q3 = fmaf(z4.w, w2[k0 + 3], q3);
    }
    h_out[(size_t)node * 64 + lane] = fmaxf((q0 + q1) + (q2 + q3), 0.f);
    asm volatile("" ::: "memory");
  }
}

// ---------------- pooling ----------------
__global__ __launch_bounds__(256) void k_pool(const float* __restrict__ h,
                                              const int* __restrict__ batch, int n,
                                              float* __restrict__ gsum,
                                              float* __restrict__ gcnt) {
  __shared__ float lsum[NGRAPHS * 64];
  __shared__ float lcnt[NGRAPHS];
  for (int i = threadIdx.x; i < NGRAPHS * 64; i += 256) lsum[i] = 0.f;
  if (threadIdx.x < NGRAPHS) lcnt[threadIdx.x] = 0.f;
  __syncthreads();
  int lane = threadIdx.x & 63, wslot = threadIdx.x >> 6;
  int wave = blockIdx.x * 4 + wslot, nw = gridDim.x * 4;
  for (int node = wave; node < n; node += nw) {
    int g = batch[node];
    atomicAdd(&lsum[g * 64 + lane], h[(size_t)node * 64 + lane]);
    if (lane == 0) atomicAdd(&lcnt[g], 1.f);
  }
  __syncthreads();
  for (int i = threadIdx.x; i < NGRAPHS * 64; i += 256) atomicAdd(&gsum[i], lsum[i]);
  if (threadIdx.x < NGRAPHS) atomicAdd(&gcnt[threadIdx.x], lcnt[threadIdx.x]);
}

// ---------------- heads ----------------
__global__ void k_head(const float* __restrict__ gsum, const float* __restrict__ gcnt,
                       const float* __restrict__ wp, const float* __restrict__ bp,
                       const float* __restrict__ wsec, const float* __restrict__ bsec,
                       float* __restrict__ out) {
  int t = threadIdx.x;
  if (t >= NGRAPHS * NCLASSES) return;
  int g = t / NCLASSES, c = t % NCLASSES;
  float inv = 1.f / fmaxf(gcnt[g], 1.f);
  float p = 0.f, s = 0.f;
  for (int d = 0; d < 64; ++d) {
    float pd = gsum[g * 64 + d] * inv;
    p = fmaf(pd, wp[d * NCLASSES + c], p);
    s = fmaf(pd, wsec[d * NCLASSES + c], s);
  }
  out[t] = p + bp[c];
  out[NGRAPHS * NCLASSES + t] = s + bsec[c];
}

extern "C" void kernel_launch(void* const* d_in, const int* in_sizes, int n_in,
                              void* d_out, int out_size, void* d_ws, size_t ws_size,
                              hipStream_t stream) {
  const float* x = (const float*)d_in[0];
  const int* ei = (const int*)d_in[1];
  const int* batch = (const int*)d_in[2];
  const float* W1 = (const float*)d_in[3];
  const float* b1 = (const float*)d_in[4];
  const float* g1 = (const float*)d_in[5];
  const float* be1 = (const float*)d_in[6];
  const float* m1 = (const float*)d_in[7];
  const float* v1 = (const float*)d_in[8];
  const float* W2 = (const float*)d_in[9];
  const float* b2 = (const float*)d_in[10];
  const float* g2 = (const float*)d_in[11];
  const float* be2 = (const float*)d_in[12];
  const float* m2 = (const float*)d_in[13];
  const float* v2 = (const float*)d_in[14];
  const float* wp = (const float*)d_in[15];
  const float* bp = (const float*)d_in[16];
  const float* wsec = (const float*)d_in[17];
  const float* bsec = (const float*)d_in[18];

  const int nE = in_sizes[1] / 2;
  const int n = in_sizes[0] / 64;
  const int NBK = (n + 255) >> 8;              // buckets of 256 dst nodes
  const int chunk = (nE + NB2 - 1) / NB2;      // edges per count/scatter block

  char* p = (char*)d_ws;
  auto alloc = [&](size_t bytes) {
    char* r = p;
    p += (bytes + 255) & ~(size_t)255;
    return r;
  };
  float* hA = (float*)alloc((size_t)n * 64 * 4);
  float* hB = (float*)alloc((size_t)n * 64 * 4);
  float* zbuf = (float*)alloc((size_t)n * 64 * 4);
  int* csr = (int*)alloc((size_t)nE * 4);
  int* offs = (int*)alloc((size_t)(n + 1) * 4);
  int* hist = (int*)alloc((size_t)NBK * NB2 * 4);
  int* hist_base = (int*)alloc((size_t)NBK * NB2 * 4);
  int* boff = (int*)alloc((size_t)(NBK + 1) * 4);
  int* partials = (int*)alloc(1024 * 4);
  float* Wf = (float*)alloc(3 * 2 * 64 * 64 * 4);
  float* Sf = (float*)alloc(3 * 2 * 64 * 4);
  float* gsum = (float*)alloc(NGRAPHS * 64 * 4);
  float* gcnt = (float*)alloc(NGRAPHS * 4);
  int2* ebuf = (int2*)zbuf;  // overlay: ebuf dead before layers use zbuf

  const int* srcA = ei;
  const int* dstA = ei + nE;

  hipMemsetAsync(gsum, 0, NGRAPHS * 64 * 4, stream);
  hipMemsetAsync(gcnt, 0, NGRAPHS * 4, stream);

  k_fold<<<(3 * 2 * 64 * 64 + 255) / 256, 256, 0, stream>>>(
      W1, b1, g1, be1, m1, v1, W2, b2, g2, be2, m2, v2, Wf, Sf);

  // ---- bucketed CSR build ----
  k_bcount<<<NB2, 256, 0, stream>>>(dstA, nE, chunk, NBK, hist);
  const int ns = NBK * NB2;
  const int nbs = (ns + SCAN_BLOCK * SCAN_ITEMS - 1) / (SCAN_BLOCK * SCAN_ITEMS);
  k_scan_partial<<<nbs, SCAN_BLOCK, 0, stream>>>(hist, ns, partials);
  k_scan_root<<<1, 64, 0, stream>>>(partials, nbs);
  k_scan_write<<<nbs, SCAN_BLOCK, 0, stream>>>(hist, ns, partials, hist_base);
  k_boff<<<(NBK + 1 + 255) / 256, 256, 0, stream>>>(hist_base, NBK, nE, boff);
  k_bscatter<<<NB2, 256, 0, stream>>>(srcA, dstA, nE, chunk, NBK, hist_base, ebuf);
  k_bsort<<<NBK, 256, 0, stream>>>(ebuf, boff, NBK, n, nE, offs, csr);

  // ---- layers ----
  const int GB = 2048;
  const int MB = 2048;
  const float* hin = x;
  float* houts[3] = {hA, hB, hA};
  for (int l = 0; l < 3; ++l) {
    k_gather<<<GB, 256, 0, stream>>>(hin, zbuf, offs, csr, n);
    k_mlp<<<MB, 256, 0, stream>>>(zbuf, houts[l], Wf + l * 8192, Sf + l * 128, n);
    hin = houts[l];
  }

  k_pool<<<512, 256, 0, stream>>>(hA, batch, n, gsum, gcnt);
  k_head<<<1, 128, 0, stream>>>(gsum, gcnt, wp, bp, wsec, bsec, (float*)d_out);
}

// Round 7
// 502.344 us; speedup vs baseline: 2.7595x; 1.1147x over previous
//
#include <hip/hip_runtime.h>

#define NCLASSES 6
#define NGRAPHS 16
#define BN_EPS 1e-5f
#define SCAN_BLOCK 256
#define SCAN_ITEMS 16  // 4096 elements per scan block
#define NB2 128        // blocks for bucket count/scatter passes

__device__ __forceinline__ float bf2f(unsigned short u) {
  union { unsigned int i; float f; } v;
  v.i = ((unsigned int)u) << 16;
  return v.f;
}
__device__ __forceinline__ unsigned short f2bf(float f) {
  union { unsigned int i; float f; } v;
  v.f = f;
  unsigned int b = v.i + 0x7FFFu + ((v.i >> 16) & 1u);
  return (unsigned short)(b >> 16);
}

// ---------------- cast x (fp32) -> bf16 ----------------
__global__ __launch_bounds__(256) void k_cast(const float* __restrict__ x,
                                              unsigned short* __restrict__ hx,
                                              int total4) {
  int i = blockIdx.x * blockDim.x + threadIdx.x;
  int stride = gridDim.x * blockDim.x;
  for (; i < total4; i += stride) {
    float4 f = reinterpret_cast<const float4*>(x)[i];
    ushort4 o;
    o.x = f2bf(f.x); o.y = f2bf(f.y); o.z = f2bf(f.z); o.w = f2bf(f.w);
    reinterpret_cast<ushort4*>(hx)[i] = o;
  }
}

// ---------------- BN-fold ----------------
__global__ void k_fold(const float* __restrict__ W1, const float* __restrict__ b1,
                       const float* __restrict__ g1, const float* __restrict__ be1,
                       const float* __restrict__ m1, const float* __restrict__ v1,
                       const float* __restrict__ W2, const float* __restrict__ b2,
                       const float* __restrict__ g2, const float* __restrict__ be2,
                       const float* __restrict__ m2, const float* __restrict__ v2,
                       float* __restrict__ Wf, float* __restrict__ Sf) {
  int idx = blockIdx.x * blockDim.x + threadIdx.x;
  if (idx >= 3 * 2 * 64 * 64) return;
  int d = idx & 63;
  int k = (idx >> 6) & 63;
  int mat = (idx >> 12) & 1;
  int l = idx >> 13;
  const float* W = mat ? W2 : W1;
  const float* b = mat ? b2 : b1;
  const float* g = mat ? g2 : g1;
  const float* be = mat ? be2 : be1;
  const float* m = mat ? m2 : m1;
  const float* v = mat ? v2 : v1;
  float scale = g[l * 64 + d] * rsqrtf(v[l * 64 + d] + BN_EPS);
  Wf[idx] = W[(l * 64 + k) * 64 + d] * scale;
  if (k == 0)
    Sf[(l * 2 + mat) * 64 + d] = be[l * 64 + d] + (b[l * 64 + d] - m[l * 64 + d]) * scale;
}

// ---------------- bucketed CSR build ----------------
__global__ __launch_bounds__(256) void k_bcount(const int* __restrict__ dst, int nE,
                                                int chunk, int nbk,
                                                int* __restrict__ hist) {
  __shared__ int lcnt[512];
  for (int i = threadIdx.x; i < nbk; i += 256) lcnt[i] = 0;
  __syncthreads();
  int blk = blockIdx.x;
  int c0 = blk * chunk, c1 = min(nE, c0 + chunk);
  for (int e = c0 + threadIdx.x; e < c1; e += 256) atomicAdd(&lcnt[dst[e] >> 8], 1);
  __syncthreads();
  for (int k = threadIdx.x; k < nbk; k += 256) hist[k * NB2 + blk] = lcnt[k];
}

__global__ __launch_bounds__(SCAN_BLOCK) void k_scan_partial(
    const int* __restrict__ in, int n, int* __restrict__ partials) {
  __shared__ int lds[SCAN_BLOCK];
  int t = threadIdx.x;
  int base = blockIdx.x * SCAN_BLOCK * SCAN_ITEMS + t * SCAN_ITEMS;
  int s = 0;
#pragma unroll
  for (int i = 0; i < SCAN_ITEMS; ++i) {
    int idx = base + i;
    if (idx < n) s += in[idx];
  }
  lds[t] = s;
  __syncthreads();
  for (int off = SCAN_BLOCK / 2; off > 0; off >>= 1) {
    if (t < off) lds[t] += lds[t + off];
    __syncthreads();
  }
  if (t == 0) partials[blockIdx.x] = lds[0];
}

__global__ void k_scan_root(int* __restrict__ partials, int nb) {
  if (threadIdx.x == 0) {
    int run = 0;
    for (int i = 0; i < nb; ++i) {
      int v = partials[i];
      partials[i] = run;
      run += v;
    }
  }
}

__global__ __launch_bounds__(SCAN_BLOCK) void k_scan_write(
    const int* __restrict__ in, int n, const int* __restrict__ partials,
    int* __restrict__ out_excl) {
  __shared__ int lds[SCAN_BLOCK];
  int t = threadIdx.x;
  int base = blockIdx.x * SCAN_BLOCK * SCAN_ITEMS + t * SCAN_ITEMS;
  int local[SCAN_ITEMS];
  int s = 0;
#pragma unroll
  for (int i = 0; i < SCAN_ITEMS; ++i) {
    int idx = base + i;
    int v = (idx < n) ? in[idx] : 0;
    local[i] = v;
    s += v;
  }
  lds[t] = s;
  __syncthreads();
  int val = s;
  for (int off = 1; off < SCAN_BLOCK; off <<= 1) {
    int tmp = (t >= off) ? lds[t - off] : 0;
    __syncthreads();
    val += tmp;
    lds[t] = val;
    __syncthreads();
  }
  int run = partials[blockIdx.x] + val - s;
#pragma unroll
  for (int i = 0; i < SCAN_ITEMS; ++i) {
    int idx = base + i;
    if (idx < n) {
      out_excl[idx] = run;
      run += local[i];
    }
  }
}

__global__ void k_boff(const int* __restrict__ hist_base, int nbk, int nE,
                       int* __restrict__ boff) {
  int t = blockIdx.x * blockDim.x + threadIdx.x;
  if (t < nbk) boff[t] = hist_base[t * NB2];
  if (t == nbk) boff[nbk] = nE;
}

// pack (src,dst) as (src<<8)|(dst&255): src<2^17 so fits in 25 bits
__global__ __launch_bounds__(256) void k_bscatter(const int* __restrict__ src,
                                                  const int* __restrict__ dst, int nE,
                                                  int chunk, int nbk,
                                                  const int* __restrict__ hist_base,
                                                  int* __restrict__ ebuf) {
  __shared__ int cur[512];
  int blk = blockIdx.x;
  for (int k = threadIdx.x; k < nbk; k += 256) cur[k] = hist_base[k * NB2 + blk];
  __syncthreads();
  int c0 = blk * chunk, c1 = min(nE, c0 + chunk);
  for (int e = c0 + threadIdx.x; e < c1; e += 256) {
    int d = dst[e];
    int pos = atomicAdd(&cur[d >> 8], 1);  // LDS atomic
    ebuf[pos] = (src[e] << 8) | (d & 255);
  }
}

__global__ __launch_bounds__(256) void k_bsort(const int* __restrict__ ebuf,
                                               const int* __restrict__ boff, int nbk,
                                               int n, int nE, int* __restrict__ offs,
                                               int* __restrict__ csr_src) {
  __shared__ int cnt[256], sc[256], cur[256];
  int b = blockIdx.x, t = threadIdx.x;
  int e0 = boff[b], e1 = boff[b + 1];
  int node0 = b << 8;
  cnt[t] = 0;
  __syncthreads();
  for (int e = e0 + t; e < e1; e += 256) atomicAdd(&cnt[ebuf[e] & 255], 1);
  __syncthreads();
  int v = cnt[t];
  sc[t] = v;
  __syncthreads();
  int val = v;
  for (int off = 1; off < 256; off <<= 1) {
    int tmp = (t >= off) ? sc[t - off] : 0;
    __syncthreads();
    val += tmp;
    sc[t] = val;
    __syncthreads();
  }
  int excl = val - v;
  int node = node0 + t;
  if (node < n) offs[node] = e0 + excl;
  cur[t] = e0 + excl;
  if (b == nbk - 1 && t == 0) offs[n] = nE;
  __syncthreads();
  for (int e = e0 + t; e < e1; e += 256) {
    int pr = ebuf[e];
    int pos = atomicAdd(&cur[pr & 255], 1);  // LDS atomic
    csr_src[pos] = ((unsigned int)pr) >> 8;
  }
}

// ---------------- gather (bf16 rows): z = h[node] + sum_neigh h ----------------
__global__ __launch_bounds__(256, 8) void k_gather(
    const unsigned short* __restrict__ h_in, unsigned short* __restrict__ z,
    const int* __restrict__ offs, const int* __restrict__ csr_src, int n) {
  const int lane = threadIdx.x & 63;
  int wave = blockIdx.x * 4 + (threadIdx.x >> 6);
  int nwaves = gridDim.x * 4;
  for (int node = wave; node < n; node += nwaves) {
    float acc = bf2f(h_in[(size_t)node * 64 + lane]);
    int e0 = __builtin_amdgcn_readfirstlane(offs[node]);
    int e1 = __builtin_amdgcn_readfirstlane(offs[node + 1]);
    int e = e0;
    float a0 = 0.f, a1 = 0.f, a2 = 0.f, a3 = 0.f;
    float a4 = 0.f, a5 = 0.f, a6 = 0.f, a7 = 0.f;
    for (; e + 7 < e1; e += 8) {
      int q0 = __builtin_amdgcn_readfirstlane(csr_src[e]);
      int q1 = __builtin_amdgcn_readfirstlane(csr_src[e + 1]);
      int q2 = __builtin_amdgcn_readfirstlane(csr_src[e + 2]);
      int q3 = __builtin_amdgcn_readfirstlane(csr_src[e + 3]);
      int q4 = __builtin_amdgcn_readfirstlane(csr_src[e + 4]);
      int q5 = __builtin_amdgcn_readfirstlane(csr_src[e + 5]);
      int q6 = __builtin_amdgcn_readfirstlane(csr_src[e + 6]);
      int q7 = __builtin_amdgcn_readfirstlane(csr_src[e + 7]);
      a0 += bf2f(h_in[(size_t)q0 * 64 + lane]);
      a1 += bf2f(h_in[(size_t)q1 * 64 + lane]);
      a2 += bf2f(h_in[(size_t)q2 * 64 + lane]);
      a3 += bf2f(h_in[(size_t)q3 * 64 + lane]);
      a4 += bf2f(h_in[(size_t)q4 * 64 + lane]);
      a5 += bf2f(h_in[(size_t)q5 * 64 + lane]);
      a6 += bf2f(h_in[(size_t)q6 * 64 + lane]);
      a7 += bf2f(h_in[(size_t)q7 * 64 + lane]);
    }
    for (; e < e1; ++e) {
      int q = __builtin_amdgcn_readfirstlane(csr_src[e]);
      a0 += bf2f(h_in[(size_t)q * 64 + lane]);
    }
    acc += ((a0 + a1) + (a2 + a3)) + ((a4 + a5) + (a6 + a7));
    z[(size_t)node * 64 + lane] = f2bf(acc);
  }
}

// ---------------- streaming MLP (bf16 io, 2 nodes/iter) ----------------
__global__ __launch_bounds__(256, 2) void k_mlp(
    const unsigned short* __restrict__ z_in, unsigned short* __restrict__ h_out,
    const float* __restrict__ Wf, const float* __restrict__ Sf, int n) {
  __shared__ __align__(16) float zb[4][2][64];
  const int lane = threadIdx.x & 63;
  const int wslot = threadIdx.x >> 6;

  float w1[64], w2[64];
#pragma unroll
  for (int k = 0; k < 64; ++k) {
    w1[k] = Wf[k * 64 + lane];
    w2[k] = Wf[4096 + k * 64 + lane];
  }
  const float s1 = Sf[lane];
  const float s2 = Sf[64 + lane];

  int wave = blockIdx.x * 4 + wslot;
  int nwaves = gridDim.x * 4;
  for (int nb = wave * 2; nb < n; nb += nwaves * 2) {
    const bool has1 = (nb + 1 < n);
    float z0 = bf2f(z_in[(size_t)nb * 64 + lane]);
    float z1 = has1 ? bf2f(z_in[(size_t)(nb + 1) * 64 + lane]) : 0.f;

    zb[wslot][0][lane] = z0;
    zb[wslot][1][lane] = z1;
    asm volatile("s_waitcnt lgkmcnt(0)" ::: "memory");

    float p00 = s1, p01 = 0.f, p02 = 0.f, p03 = 0.f;
    float p10 = s1, p11 = 0.f, p12 = 0.f, p13 = 0.f;
#pragma unroll
    for (int k0 = 0; k0 < 64; k0 += 4) {
      float4 a = *reinterpret_cast<const float4*>(&zb[wslot][0][k0]);
      float4 b = *reinterpret_cast<const float4*>(&zb[wslot][1][k0]);
      p00 = fmaf(a.x, w1[k0 + 0], p00);
      p10 = fmaf(b.x, w1[k0 + 0], p10);
      p01 = fmaf(a.y, w1[k0 + 1], p01);
      p11 = fmaf(b.y, w1[k0 + 1], p11);
      p02 = fmaf(a.z, w1[k0 + 2], p02);
      p12 = fmaf(b.z, w1[k0 + 2], p12);
      p03 = fmaf(a.w, w1[k0 + 3], p03);
      p13 = fmaf(b.w, w1[k0 + 3], p13);
    }
    float o0 = fmaxf((p00 + p01) + (p02 + p03), 0.f);
    float o1 = fmaxf((p10 + p11) + (p12 + p13), 0.f);

    asm volatile("" ::: "memory");
    zb[wslot][0][lane] = o0;
    zb[wslot][1][lane] = o1;
    asm volatile("s_waitcnt lgkmcnt(0)" ::: "memory");

    float q00 = s2, q01 = 0.f, q02 = 0.f, q03 = 0.f;
    float q10 = s2, q11 = 0.f, q12 = 0.f, q13 = 0.f;
#pragma unroll
    for (int k0 = 0; k0 < 64; k0 += 4) {
      float4 a = *reinterpret_cast<const float4*>(&zb[wslot][0][k0]);
      float4 b = *reinterpret_cast<const float4*>(&zb[wslot][1][k0]);
      q00 = fmaf(a.x, w2[k0 + 0], q00);
      q10 = fmaf(b.x, w2[k0 + 0], q10);
      q01 = fmaf(a.y, w2[k0 + 1], q01);
      q11 = fmaf(b.y, w2[k0 + 1], q11);
      q02 = fmaf(a.z, w2[k0 + 2], q02);
      q12 = fmaf(b.z, w2[k0 + 2], q12);
      q03 = fmaf(a.w, w2[k0 + 3], q03);
      q13 = fmaf(b.w, w2[k0 + 3], q13);
    }
    h_out[(size_t)nb * 64 + lane] = f2bf(fmaxf((q00 + q01) + (q02 + q03), 0.f));
    if (has1)
      h_out[(size_t)(nb + 1) * 64 + lane] = f2bf(fmaxf((q10 + q11) + (q12 + q13), 0.f));
    asm volatile("" ::: "memory");
  }
}

// ---------------- pooling (bf16 h) ----------------
__global__ __launch_bounds__(256) void k_pool(const unsigned short* __restrict__ h,
                                              const int* __restrict__ batch, int n,
                                              float* __restrict__ gsum,
                                              float* __restrict__ gcnt) {
  __shared__ float lsum[NGRAPHS * 64];
  __shared__ float lcnt[NGRAPHS];
  for (int i = threadIdx.x; i < NGRAPHS * 64; i += 256) lsum[i] = 0.f;
  if (threadIdx.x < NGRAPHS) lcnt[threadIdx.x] = 0.f;
  __syncthreads();
  int lane = threadIdx.x & 63, wslot = threadIdx.x >> 6;
  int wave = blockIdx.x * 4 + wslot, nw = gridDim.x * 4;
  for (int node = wave; node < n; node += nw) {
    int g = batch[node];
    atomicAdd(&lsum[g * 64 + lane], bf2f(h[(size_t)node * 64 + lane]));
    if (lane == 0) atomicAdd(&lcnt[g], 1.f);
  }
  __syncthreads();
  for (int i = threadIdx.x; i < NGRAPHS * 64; i += 256) atomicAdd(&gsum[i], lsum[i]);
  if (threadIdx.x < NGRAPHS) atomicAdd(&gcnt[threadIdx.x], lcnt[threadIdx.x]);
}

// ---------------- heads ----------------
__global__ void k_head(const float* __restrict__ gsum, const float* __restrict__ gcnt,
                       const float* __restrict__ wp, const float* __restrict__ bp,
                       const float* __restrict__ wsec, const float* __restrict__ bsec,
                       float* __restrict__ out) {
  int t = threadIdx.x;
  if (t >= NGRAPHS * NCLASSES) return;
  int g = t / NCLASSES, c = t % NCLASSES;
  float inv = 1.f / fmaxf(gcnt[g], 1.f);
  float p = 0.f, s = 0.f;
  for (int d = 0; d < 64; ++d) {
    float pd = gsum[g * 64 + d] * inv;
    p = fmaf(pd, wp[d * NCLASSES + c], p);
    s = fmaf(pd, wsec[d * NCLASSES + c], s);
  }
  out[t] = p + bp[c];
  out[NGRAPHS * NCLASSES + t] = s + bsec[c];
}

extern "C" void kernel_launch(void* const* d_in, const int* in_sizes, int n_in,
                              void* d_out, int out_size, void* d_ws, size_t ws_size,
                              hipStream_t stream) {
  const float* x = (const float*)d_in[0];
  const int* ei = (const int*)d_in[1];
  const int* batch = (const int*)d_in[2];
  const float* W1 = (const float*)d_in[3];
  const float* b1 = (const float*)d_in[4];
  const float* g1 = (const float*)d_in[5];
  const float* be1 = (const float*)d_in[6];
  const float* m1 = (const float*)d_in[7];
  const float* v1 = (const float*)d_in[8];
  const float* W2 = (const float*)d_in[9];
  const float* b2 = (const float*)d_in[10];
  const float* g2 = (const float*)d_in[11];
  const float* be2 = (const float*)d_in[12];
  const float* m2 = (const float*)d_in[13];
  const float* v2 = (const float*)d_in[14];
  const float* wp = (const float*)d_in[15];
  const float* bp = (const float*)d_in[16];
  const float* wsec = (const float*)d_in[17];
  const float* bsec = (const float*)d_in[18];

  const int nE = in_sizes[1] / 2;
  const int n = in_sizes[0] / 64;
  const int NBK = (n + 255) >> 8;          // buckets of 256 dst nodes
  const int chunk = (nE + NB2 - 1) / NB2;  // edges per count/scatter block

  char* p = (char*)d_ws;
  auto alloc = [&](size_t bytes) {
    char* r = p;
    p += (bytes + 255) & ~(size_t)255;
    return r;
  };
  unsigned short* hx = (unsigned short*)alloc((size_t)n * 64 * 2);
  unsigned short* hA = (unsigned short*)alloc((size_t)n * 64 * 2);
  unsigned short* hB = (unsigned short*)alloc((size_t)n * 64 * 2);
  unsigned short* zbuf = (unsigned short*)alloc((size_t)n * 64 * 2);
  int* csr = (int*)alloc((size_t)nE * 4);
  int* offs = (int*)alloc((size_t)(n + 1) * 4);
  int* hist = (int*)alloc((size_t)NBK * NB2 * 4);
  int* hist_base = (int*)alloc((size_t)NBK * NB2 * 4);
  int* boff = (int*)alloc((size_t)(NBK + 1) * 4);
  int* partials = (int*)alloc(1024 * 4);
  float* Wf = (float*)alloc(3 * 2 * 64 * 64 * 4);
  float* Sf = (float*)alloc(3 * 2 * 64 * 4);
  float* gsum = (float*)alloc(NGRAPHS * 64 * 4);
  float* gcnt = (float*)alloc(NGRAPHS * 4);
  int* ebuf = (int*)zbuf;  // overlay: ebuf (6.4MB) dead before layers use zbuf (12.8MB)

  const int* srcA = ei;
  const int* dstA = ei + nE;

  hipMemsetAsync(gsum, 0, NGRAPHS * 64 * 4, stream);
  hipMemsetAsync(gcnt, 0, NGRAPHS * 4, stream);

  k_cast<<<1024, 256, 0, stream>>>(x, hx, n * 64 / 4);
  k_fold<<<(3 * 2 * 64 * 64 + 255) / 256, 256, 0, stream>>>(
      W1, b1, g1, be1, m1, v1, W2, b2, g2, be2, m2, v2, Wf, Sf);

  // ---- bucketed CSR build ----
  k_bcount<<<NB2, 256, 0, stream>>>(dstA, nE, chunk, NBK, hist);
  const int ns = NBK * NB2;
  const int nbs = (ns + SCAN_BLOCK * SCAN_ITEMS - 1) / (SCAN_BLOCK * SCAN_ITEMS);
  k_scan_partial<<<nbs, SCAN_BLOCK, 0, stream>>>(hist, ns, partials);
  k_scan_root<<<1, 64, 0, stream>>>(partials, nbs);
  k_scan_write<<<nbs, SCAN_BLOCK, 0, stream>>>(hist, ns, partials, hist_base);
  k_boff<<<(NBK + 1 + 255) / 256, 256, 0, stream>>>(hist_base, NBK, nE, boff);
  k_bscatter<<<NB2, 256, 0, stream>>>(srcA, dstA, nE, chunk, NBK, hist_base, ebuf);
  k_bsort<<<NBK, 256, 0, stream>>>(ebuf, boff, NBK, n, nE, offs, csr);

  // ---- layers ----
  const int GB = 2048;
  const int MB = 2048;
  const unsigned short* hin = hx;
  unsigned short* houts[3] = {hA, hB, hA};
  for (int l = 0; l < 3; ++l) {
    k_gather<<<GB, 256, 0, stream>>>(hin, zbuf, offs, csr, n);
    k_mlp<<<MB, 256, 0, stream>>>(zbuf, houts[l], Wf + l * 8192, Sf + l * 128, n);
    hin = houts[l];
  }

  k_pool<<<512, 256, 0, stream>>>(hA, batch, n, gsum, gcnt);
  k_head<<<1, 128, 0, stream>>>(gsum, gcnt, wp, bp, wsec, bsec, (float*)d_out);
}

// Round 9
// 391.783 us; speedup vs baseline: 3.5382x; 1.2822x over previous
//
#include <hip/hip_runtime.h>
#include <hip/hip_bf16.h>

#define NCLASSES 6
#define NGRAPHS 16
#define BN_EPS 1e-5f
#define SCAN_BLOCK 256
#define SCAN_ITEMS 16  // 4096 elements per scan block
#define NB2 128        // blocks for bucket count/scatter passes

typedef __attribute__((ext_vector_type(8))) short short8v;
typedef __attribute__((ext_vector_type(4))) float float4v;

__device__ __forceinline__ float bf2f(unsigned short u) {
  union { unsigned int i; float f; } v;
  v.i = ((unsigned int)u) << 16;
  return v.f;
}
__device__ __forceinline__ unsigned short f2bf(float f) {
  union { unsigned int i; float f; } v;
  v.f = f;
  unsigned int b = v.i + 0x7FFFu + ((v.i >> 16) & 1u);
  return (unsigned short)(b >> 16);
}

// ---------------- cast x (fp32) -> bf16 ----------------
__global__ __launch_bounds__(256) void k_cast(const float* __restrict__ x,
                                              unsigned short* __restrict__ hx,
                                              int total4) {
  int i = blockIdx.x * blockDim.x + threadIdx.x;
  int stride = gridDim.x * blockDim.x;
  for (; i < total4; i += stride) {
    float4 f = reinterpret_cast<const float4*>(x)[i];
    ushort4 o;
    o.x = f2bf(f.x); o.y = f2bf(f.y); o.z = f2bf(f.z); o.w = f2bf(f.w);
    reinterpret_cast<ushort4*>(hx)[i] = o;
  }
}

// ---------------- BN-fold into MFMA-fragment-ordered bf16 weights ----------------
// Wfb flat idx = ((((l*2 + mat)*2 + h)*4 + t)*64 + lane)*8 + j
//   holds W_mat[l][k][d]*scale with k = 32h + 8*(lane>>4) + j, d = 16t + (lane&15)
// Sf[(l*2+mat)*64 + d] = be + (b - m)*scale
__global__ void k_fold(const float* __restrict__ W1, const float* __restrict__ b1,
                       const float* __restrict__ g1, const float* __restrict__ be1,
                       const float* __restrict__ m1, const float* __restrict__ v1,
                       const float* __restrict__ W2, const float* __restrict__ b2,
                       const float* __restrict__ g2, const float* __restrict__ be2,
                       const float* __restrict__ m2, const float* __restrict__ v2,
                       unsigned short* __restrict__ Wfb, float* __restrict__ Sf) {
  int idx = blockIdx.x * blockDim.x + threadIdx.x;
  if (idx >= 3 * 2 * 2 * 4 * 64 * 8) return;  // 24576
  int j = idx & 7;
  int lane = (idx >> 3) & 63;
  int t = (idx >> 9) & 3;
  int h = (idx >> 11) & 1;
  int mat = (idx >> 12) & 1;
  int l = idx >> 13;
  int k = 32 * h + 8 * (lane >> 4) + j;
  int d = 16 * t + (lane & 15);
  const float* W = mat ? W2 : W1;
  const float* b = mat ? b2 : b1;
  const float* g = mat ? g2 : g1;
  const float* be = mat ? be2 : be1;
  const float* m = mat ? m2 : m1;
  const float* v = mat ? v2 : v1;
  float scale = g[l * 64 + d] * rsqrtf(v[l * 64 + d] + BN_EPS);
  Wfb[idx] = f2bf(W[(l * 64 + k) * 64 + d] * scale);
  if (h == 0 && j == 0)
    Sf[(l * 2 + mat) * 64 + d] = be[l * 64 + d] + (b[l * 64 + d] - m[l * 64 + d]) * scale;
}

// ---------------- bucketed CSR build ----------------
__global__ __launch_bounds__(256) void k_bcount(const int* __restrict__ dst, int nE,
                                                int chunk, int nbk,
                                                int* __restrict__ hist) {
  __shared__ int lcnt[512];
  for (int i = threadIdx.x; i < nbk; i += 256) lcnt[i] = 0;
  __syncthreads();
  int blk = blockIdx.x;
  int c0 = blk * chunk, c1 = min(nE, c0 + chunk);
  for (int e = c0 + threadIdx.x; e < c1; e += 256) atomicAdd(&lcnt[dst[e] >> 8], 1);
  __syncthreads();
  for (int k = threadIdx.x; k < nbk; k += 256) hist[k * NB2 + blk] = lcnt[k];
}

__global__ __launch_bounds__(SCAN_BLOCK) void k_scan_partial(
    const int* __restrict__ in, int n, int* __restrict__ partials) {
  __shared__ int lds[SCAN_BLOCK];
  int t = threadIdx.x;
  int base = blockIdx.x * SCAN_BLOCK * SCAN_ITEMS + t * SCAN_ITEMS;
  int s = 0;
#pragma unroll
  for (int i = 0; i < SCAN_ITEMS; ++i) {
    int idx = base + i;
    if (idx < n) s += in[idx];
  }
  lds[t] = s;
  __syncthreads();
  for (int off = SCAN_BLOCK / 2; off > 0; off >>= 1) {
    if (t < off) lds[t] += lds[t + off];
    __syncthreads();
  }
  if (t == 0) partials[blockIdx.x] = lds[0];
}

__global__ void k_scan_root(int* __restrict__ partials, int nb) {
  if (threadIdx.x == 0) {
    int run = 0;
    for (int i = 0; i < nb; ++i) {
      int v = partials[i];
      partials[i] = run;
      run += v;
    }
  }
}

__global__ __launch_bounds__(SCAN_BLOCK) void k_scan_write(
    const int* __restrict__ in, int n, const int* __restrict__ partials,
    int* __restrict__ out_excl) {
  __shared__ int lds[SCAN_BLOCK];
  int t = threadIdx.x;
  int base = blockIdx.x * SCAN_BLOCK * SCAN_ITEMS + t * SCAN_ITEMS;
  int local[SCAN_ITEMS];
  int s = 0;
#pragma unroll
  for (int i = 0; i < SCAN_ITEMS; ++i) {
    int idx = base + i;
    int v = (idx < n) ? in[idx] : 0;
    local[i] = v;
    s += v;
  }
  lds[t] = s;
  __syncthreads();
  int val = s;
  for (int off = 1; off < SCAN_BLOCK; off <<= 1) {
    int tmp = (t >= off) ? lds[t - off] : 0;
    __syncthreads();
    val += tmp;
    lds[t] = val;
    __syncthreads();
  }
  int run = partials[blockIdx.x] + val - s;
#pragma unroll
  for (int i = 0; i < SCAN_ITEMS; ++i) {
    int idx = base + i;
    if (idx < n) {
      out_excl[idx] = run;
      run += local[i];
    }
  }
}

__global__ void k_boff(const int* __restrict__ hist_base, int nbk, int nE,
                       int* __restrict__ boff) {
  int t = blockIdx.x * blockDim.x + threadIdx.x;
  if (t < nbk) boff[t] = hist_base[t * NB2];
  if (t == nbk) boff[nbk] = nE;
}

__global__ __launch_bounds__(256) void k_bscatter(const int* __restrict__ src,
                                                  const int* __restrict__ dst, int nE,
                                                  int chunk, int nbk,
                                                  const int* __restrict__ hist_base,
                                                  int* __restrict__ ebuf) {
  __shared__ int cur[512];
  int blk = blockIdx.x;
  for (int k = threadIdx.x; k < nbk; k += 256) cur[k] = hist_base[k * NB2 + blk];
  __syncthreads();
  int c0 = blk * chunk, c1 = min(nE, c0 + chunk);
  for (int e = c0 + threadIdx.x; e < c1; e += 256) {
    int d = dst[e];
    int pos = atomicAdd(&cur[d >> 8], 1);  // LDS atomic
    ebuf[pos] = (src[e] << 8) | (d & 255);
  }
}

__global__ __launch_bounds__(256) void k_bsort(const int* __restrict__ ebuf,
                                               const int* __restrict__ boff, int nbk,
                                               int n, int nE, int* __restrict__ offs,
                                               int* __restrict__ csr_src) {
  __shared__ int cnt[256], sc[256], cur[256];
  int b = blockIdx.x, t = threadIdx.x;
  int e0 = boff[b], e1 = boff[b + 1];
  int node0 = b << 8;
  cnt[t] = 0;
  __syncthreads();
  for (int e = e0 + t; e < e1; e += 256) atomicAdd(&cnt[ebuf[e] & 255], 1);
  __syncthreads();
  int v = cnt[t];
  sc[t] = v;
  __syncthreads();
  int val = v;
  for (int off = 1; off < 256; off <<= 1) {
    int tmp = (t >= off) ? sc[t - off] : 0;
    __syncthreads();
    val += tmp;
    sc[t] = val;
    __syncthreads();
  }
  int excl = val - v;
  int node = node0 + t;
  if (node < n) offs[node] = e0 + excl;
  cur[t] = e0 + excl;
  if (b == nbk - 1 && t == 0) offs[n] = nE;
  __syncthreads();
  for (int e = e0 + t; e < e1; e += 256) {
    int pr = ebuf[e];
    int pos = atomicAdd(&cur[pr & 255], 1);  // LDS atomic
    csr_src[pos] = ((unsigned int)pr) >> 8;
  }
}

// ---------------- gather (bf16 rows): z = h[node] + sum_neigh h ----------------
__global__ __launch_bounds__(256, 8) void k_gather(
    const unsigned short* __restrict__ h_in, unsigned short* __restrict__ z,
    const int* __restrict__ offs, const int* __restrict__ csr_src, int n) {
  const int lane = threadIdx.x & 63;
  int wave = blockIdx.x * 4 + (threadIdx.x >> 6);
  int nwaves = gridDim.x * 4;
  for (int node = wave; node < n; node += nwaves) {
    float acc = bf2f(h_in[(size_t)node * 64 + lane]);
    int e0 = __builtin_amdgcn_readfirstlane(offs[node]);
    int e1 = __builtin_amdgcn_readfirstlane(offs[node + 1]);
    int e = e0;
    float a0 = 0.f, a1 = 0.f, a2 = 0.f, a3 = 0.f;
    float a4 = 0.f, a5 = 0.f, a6 = 0.f, a7 = 0.f;
    for (; e + 7 < e1; e += 8) {
      int q0 = __builtin_amdgcn_readfirstlane(csr_src[e]);
      int q1 = __builtin_amdgcn_readfirstlane(csr_src[e + 1]);
      int q2 = __builtin_amdgcn_readfirstlane(csr_src[e + 2]);
      int q3 = __builtin_amdgcn_readfirstlane(csr_src[e + 3]);
      int q4 = __builtin_amdgcn_readfirstlane(csr_src[e + 4]);
      int q5 = __builtin_amdgcn_readfirstlane(csr_src[e + 5]);
      int q6 = __builtin_amdgcn_readfirstlane(csr_src[e + 6]);
      int q7 = __builtin_amdgcn_readfirstlane(csr_src[e + 7]);
      a0 += bf2f(h_in[(size_t)q0 * 64 + lane]);
      a1 += bf2f(h_in[(size_t)q1 * 64 + lane]);
      a2 += bf2f(h_in[(size_t)q2 * 64 + lane]);
      a3 += bf2f(h_in[(size_t)q3 * 64 + lane]);
      a4 += bf2f(h_in[(size_t)q4 * 64 + lane]);
      a5 += bf2f(h_in[(size_t)q5 * 64 + lane]);
      a6 += bf2f(h_in[(size_t)q6 * 64 + lane]);
      a7 += bf2f(h_in[(size_t)q7 * 64 + lane]);
    }
    for (; e < e1; ++e) {
      int q = __builtin_amdgcn_readfirstlane(csr_src[e]);
      a0 += bf2f(h_in[(size_t)q * 64 + lane]);
    }
    acc += ((a0 + a1) + (a2 + a3)) + ((a4 + a5) + (a6 + a7));
    z[(size_t)node * 64 + lane] = f2bf(acc);
  }
}

// ---------------- MFMA MLP: h' = relu(bn2(relu(bn1(z@W1))@W2)) ----------------
// Per wave: 16-node tile. z A-frags: row = lane&15, k = 32h + 8*(lane>>4) + j.
// Weights pre-packed frag-ordered (k_fold). D layout: row=(lane>>4)*4+r, col=lane&15.
// Mid-transpose + coalesced store via wave-private XOR-swizzled LDS tile.
__global__ __launch_bounds__(256, 2) void k_mlp(
    const unsigned short* __restrict__ z_in, unsigned short* __restrict__ h_out,
    const unsigned short* __restrict__ Wfb, const float* __restrict__ Sf, int n) {
  __shared__ __align__(16) unsigned short tile[4][16 * 64];  // 2KB per wave
  const int lane = threadIdx.x & 63;
  const int wslot = threadIdx.x >> 6;
  const int g = lane >> 4, c = lane & 15;
  unsigned short* T = tile[wslot];

  // weight frags [t][h] for each matmul; contiguous ushort8 per lane
  const short8v* Wv = reinterpret_cast<const short8v*>(Wfb);
  short8v w1f[4][2], w2f[4][2];
#pragma unroll
  for (int h = 0; h < 2; ++h)
#pragma unroll
    for (int t = 0; t < 4; ++t) {
      w1f[t][h] = Wv[((0 * 2 + h) * 4 + t) * 64 + lane];
      w2f[t][h] = Wv[((1 * 2 + h) * 4 + t) * 64 + lane];
    }
  float s1v[4], s2v[4];
#pragma unroll
  for (int t = 0; t < 4; ++t) {
    s1v[t] = Sf[c + 16 * t];
    s2v[t] = Sf[64 + c + 16 * t];
  }

  int wave = blockIdx.x * 4 + wslot;
  int nwaves = gridDim.x * 4;
  int ntiles = (n + 15) >> 4;
  for (int tt = wave; tt < ntiles; tt += nwaves) {
    int node0 = tt << 4;
    int arow = node0 + c;
    if (arow >= n) arow = n - 1;
    const short8v* zrow = reinterpret_cast<const short8v*>(z_in + (size_t)arow * 64);
    short8v a0 = zrow[g];      // k = 8g..8g+7
    short8v a1 = zrow[g + 4];  // k = 32+8g..

    float4v c1[4];
#pragma unroll
    for (int t = 0; t < 4; ++t) {
      float4v acc = {s1v[t], s1v[t], s1v[t], s1v[t]};
      acc = __builtin_amdgcn_mfma_f32_16x16x32_bf16(a0, w1f[t][0], acc, 0, 0, 0);
      acc = __builtin_amdgcn_mfma_f32_16x16x32_bf16(a1, w1f[t][1], acc, 0, 0, 0);
      c1[t] = acc;
    }

    // relu -> bf16 -> swizzled LDS (row m = 4g+r, col n1 = c+16t)
#pragma unroll
    for (int t = 0; t < 4; ++t)
#pragma unroll
      for (int r = 0; r < 4; ++r) {
        int m = 4 * g + r;
        int byte = ((c + 16 * t) * 2) ^ ((m & 7) << 4);
        T[(m * 128 + byte) >> 1] = f2bf(fmaxf(c1[t][r], 0.f));
      }
    asm volatile("s_waitcnt lgkmcnt(0)" ::: "memory");
    __builtin_amdgcn_sched_barrier(0);

    // A2-frags: row c, k = 32h + 8g + j
    int rb = c * 128;
    int sw = (c & 7) << 4;
    short8v a20 = *reinterpret_cast<const short8v*>(&T[(rb + ((g * 16) ^ sw)) >> 1]);
    short8v a21 = *reinterpret_cast<const short8v*>(&T[(rb + ((64 + g * 16) ^ sw)) >> 1]);
    asm volatile("s_waitcnt lgkmcnt(0)" ::: "memory");
    __builtin_amdgcn_sched_barrier(0);

    float4v c2[4];
#pragma unroll
    for (int t = 0; t < 4; ++t) {
      float4v acc = {s2v[t], s2v[t], s2v[t], s2v[t]};
      acc = __builtin_amdgcn_mfma_f32_16x16x32_bf16(a20, w2f[t][0], acc, 0, 0, 0);
      acc = __builtin_amdgcn_mfma_f32_16x16x32_bf16(a21, w2f[t][1], acc, 0, 0, 0);
      c2[t] = acc;
    }

    // relu -> bf16 -> swizzled LDS
#pragma unroll
    for (int t = 0; t < 4; ++t)
#pragma unroll
      for (int r = 0; r < 4; ++r) {
        int m = 4 * g + r;
        int byte = ((c + 16 * t) * 2) ^ ((m & 7) << 4);
        T[(m * 128 + byte) >> 1] = f2bf(fmaxf(c2[t][r], 0.f));
      }
    asm volatile("s_waitcnt lgkmcnt(0)" ::: "memory");
    __builtin_amdgcn_sched_barrier(0);

    // coalesced store: lane -> row rho = lane>>2, 32B chunk (lane&3)
    {
      int rho = lane >> 2;
      int node = node0 + rho;
      if (node < n) {
        int cb = (lane & 3) * 32;
        int swr = (rho & 7) << 4;
        short8v v0 = *reinterpret_cast<const short8v*>(&T[(rho * 128 + (cb ^ swr)) >> 1]);
        short8v v1 =
            *reinterpret_cast<const short8v*>(&T[(rho * 128 + ((cb + 16) ^ swr)) >> 1]);
        short8v* orow = reinterpret_cast<short8v*>(h_out + (size_t)node * 64);
        orow[(lane & 3) * 2] = v0;
        orow[(lane & 3) * 2 + 1] = v1;
      }
    }
    asm volatile("s_waitcnt lgkmcnt(0)" ::: "memory");
    __builtin_amdgcn_sched_barrier(0);
  }
}

// ---------------- pooling (bf16 h) ----------------
__global__ __launch_bounds__(256) void k_pool(const unsigned short* __restrict__ h,
                                              const int* __restrict__ batch, int n,
                                              float* __restrict__ gsum,
                                              float* __restrict__ gcnt) {
  __shared__ float lsum[NGRAPHS * 64];
  __shared__ float lcnt[NGRAPHS];
  for (int i = threadIdx.x; i < NGRAPHS * 64; i += 256) lsum[i] = 0.f;
  if (threadIdx.x < NGRAPHS) lcnt[threadIdx.x] = 0.f;
  __syncthreads();
  int lane = threadIdx.x & 63, wslot = threadIdx.x >> 6;
  int wave = blockIdx.x * 4 + wslot, nw = gridDim.x * 4;
  for (int node = wave; node < n; node += nw) {
    int g = batch[node];
    atomicAdd(&lsum[g * 64 + lane], bf2f(h[(size_t)node * 64 + lane]));
    if (lane == 0) atomicAdd(&lcnt[g], 1.f);
  }
  __syncthreads();
  for (int i = threadIdx.x; i < NGRAPHS * 64; i += 256) atomicAdd(&gsum[i], lsum[i]);
  if (threadIdx.x < NGRAPHS) atomicAdd(&gcnt[threadIdx.x], lcnt[threadIdx.x]);
}

// ---------------- heads ----------------
__global__ void k_head(const float* __restrict__ gsum, const float* __restrict__ gcnt,
                       const float* __restrict__ wp, const float* __restrict__ bp,
                       const float* __restrict__ wsec, const float* __restrict__ bsec,
                       float* __restrict__ out) {
  int t = threadIdx.x;
  if (t >= NGRAPHS * NCLASSES) return;
  int g = t / NCLASSES, c = t % NCLASSES;
  float inv = 1.f / fmaxf(gcnt[g], 1.f);
  float p = 0.f, s = 0.f;
  for (int d = 0; d < 64; ++d) {
    float pd = gsum[g * 64 + d] * inv;
    p = fmaf(pd, wp[d * NCLASSES + c], p);
    s = fmaf(pd, wsec[d * NCLASSES + c], s);
  }
  out[t] = p + bp[c];
  out[NGRAPHS * NCLASSES + t] = s + bsec[c];
}

extern "C" void kernel_launch(void* const* d_in, const int* in_sizes, int n_in,
                              void* d_out, int out_size, void* d_ws, size_t ws_size,
                              hipStream_t stream) {
  const float* x = (const float*)d_in[0];
  const int* ei = (const int*)d_in[1];
  const int* batch = (const int*)d_in[2];
  const float* W1 = (const float*)d_in[3];
  const float* b1 = (const float*)d_in[4];
  const float* g1 = (const float*)d_in[5];
  const float* be1 = (const float*)d_in[6];
  const float* m1 = (const float*)d_in[7];
  const float* v1 = (const float*)d_in[8];
  const float* W2 = (const float*)d_in[9];
  const float* b2 = (const float*)d_in[10];
  const float* g2 = (const float*)d_in[11];
  const float* be2 = (const float*)d_in[12];
  const float* m2 = (const float*)d_in[13];
  const float* v2 = (const float*)d_in[14];
  const float* wp = (const float*)d_in[15];
  const float* bp = (const float*)d_in[16];
  const float* wsec = (const float*)d_in[17];
  const float* bsec = (const float*)d_in[18];

  const int nE = in_sizes[1] / 2;
  const int n = in_sizes[0] / 64;
  const int NBK = (n + 255) >> 8;          // buckets of 256 dst nodes
  const int chunk = (nE + NB2 - 1) / NB2;  // edges per count/scatter block

  char* p = (char*)d_ws;
  auto alloc = [&](size_t bytes) {
    char* r = p;
    p += (bytes + 255) & ~(size_t)255;
    return r;
  };
  unsigned short* hx = (unsigned short*)alloc((size_t)n * 64 * 2);
  unsigned short* hA = (unsigned short*)alloc((size_t)n * 64 * 2);
  unsigned short* hB = (unsigned short*)alloc((size_t)n * 64 * 2);
  unsigned short* zbuf = (unsigned short*)alloc((size_t)n * 64 * 2);
  int* csr = (int*)alloc((size_t)nE * 4);
  int* offs = (int*)alloc((size_t)(n + 1) * 4);
  int* hist = (int*)alloc((size_t)NBK * NB2 * 4);
  int* hist_base = (int*)alloc((size_t)NBK * NB2 * 4);
  int* boff = (int*)alloc((size_t)(NBK + 1) * 4);
  int* partials = (int*)alloc(1024 * 4);
  unsigned short* Wfb = (unsigned short*)alloc(3 * 2 * 2 * 4 * 64 * 8 * 2);
  float* Sf = (float*)alloc(3 * 2 * 64 * 4);
  float* gsum = (float*)alloc(NGRAPHS * 64 * 4);
  float* gcnt = (float*)alloc(NGRAPHS * 4);
  int* ebuf = (int*)zbuf;  // overlay: ebuf (6.4MB) dead before layers use zbuf (12.8MB)

  const int* srcA = ei;
  const int* dstA = ei + nE;

  hipMemsetAsync(gsum, 0, NGRAPHS * 64 * 4, stream);
  hipMemsetAsync(gcnt, 0, NGRAPHS * 4, stream);

  k_cast<<<1024, 256, 0, stream>>>(x, hx, n * 64 / 4);
  k_fold<<<96, 256, 0, stream>>>(W1, b1, g1, be1, m1, v1, W2, b2, g2, be2, m2, v2,
                                 Wfb, Sf);

  // ---- bucketed CSR build ----
  k_bcount<<<NB2, 256, 0, stream>>>(dstA, nE, chunk, NBK, hist);
  const int ns = NBK * NB2;
  const int nbs = (ns + SCAN_BLOCK * SCAN_ITEMS - 1) / (SCAN_BLOCK * SCAN_ITEMS);
  k_scan_partial<<<nbs, SCAN_BLOCK, 0, stream>>>(hist, ns, partials);
  k_scan_root<<<1, 64, 0, stream>>>(partials, nbs);
  k_scan_write<<<nbs, SCAN_BLOCK, 0, stream>>>(hist, ns, partials, hist_base);
  k_boff<<<(NBK + 1 + 255) / 256, 256, 0, stream>>>(hist_base, NBK, nE, boff);
  k_bscatter<<<NB2, 256, 0, stream>>>(srcA, dstA, nE, chunk, NBK, hist_base, ebuf);
  k_bsort<<<NBK, 256, 0, stream>>>(ebuf, boff, NBK, n, nE, offs, csr);

  // ---- layers ----
  const int GB = 2048;
  const int MB = 512;
  const unsigned short* hin = hx;
  unsigned short* houts[3] = {hA, hB, hA};
  for (int l = 0; l < 3; ++l) {
    k_gather<<<GB, 256, 0, stream>>>(hin, zbuf, offs, csr, n);
    k_mlp<<<MB, 256, 0, stream>>>(zbuf, houts[l], Wfb + l * 8192, Sf + l * 128, n);
    hin = houts[l];
  }

  k_pool<<<512, 256, 0, stream>>>(hA, batch, n, gsum, gcnt);
  k_head<<<1, 128, 0, stream>>>(gsum, gcnt, wp, bp, wsec, bsec, (float*)d_out);
}